// Round 1
// baseline (717.134 us; speedup 1.0000x reference)
//
#include <hip/hip_runtime.h>

#define N_NODES 100000
#define N_EDGES 1600000

typedef __attribute__((ext_vector_type(8))) short short8;   // 8 bf16 (4 VGPR) MFMA frag
typedef __attribute__((ext_vector_type(4))) float f32x4;    // MFMA accumulator

__device__ inline unsigned short f2bf(float f) {
    unsigned int u = __builtin_bit_cast(unsigned int, f);
    u += 0x7fffu + ((u >> 16) & 1u);   // round-to-nearest-even
    return (unsigned short)(u >> 16);
}
__device__ inline float bf2f(unsigned short h) {
    unsigned int u = ((unsigned int)h) << 16;
    return __builtin_bit_cast(float, u);
}

// ---- degree histogram (also CSR counts) ----
__global__ __launch_bounds__(256) void k_deg(const int* __restrict__ src, const int* __restrict__ dst,
                                             int* __restrict__ deg_src, int* __restrict__ deg_dst) {
    int e = blockIdx.x * 256 + threadIdx.x;   // grid sized exactly E/256
    atomicAdd(&deg_src[src[e]], 1);
    atomicAdd(&deg_dst[dst[e]], 1);
}

// ---- norms: deg>0 ? rsqrt(deg) : 1 ----
__global__ __launch_bounds__(256) void k_norms(const int* __restrict__ deg_src, const int* __restrict__ deg_dst,
                                               float* __restrict__ out_norm, float* __restrict__ in_norm) {
    int i = blockIdx.x * 256 + threadIdx.x;
    if (i >= N_NODES) return;
    int ds = deg_src[i], dd = deg_dst[i];
    out_norm[i] = ds > 0 ? rsqrtf((float)ds) : 1.0f;
    in_norm[i]  = dd > 0 ? rsqrtf((float)dd) : 1.0f;
}

// ---- xb = bf16(x * out_norm[row]) ----
__global__ __launch_bounds__(256) void k_xb(const float* __restrict__ x, const float* __restrict__ out_norm,
                                            unsigned short* __restrict__ xb) {
    int tid = blockIdx.x * 256 + threadIdx.x;   // grid exactly N*32
    int row = tid >> 5;
    float4 v = ((const float4*)x)[tid];
    float w = out_norm[row];
    unsigned int lo = (unsigned int)f2bf(v.x * w) | ((unsigned int)f2bf(v.y * w) << 16);
    unsigned int hi = (unsigned int)f2bf(v.z * w) | ((unsigned int)f2bf(v.w * w) << 16);
    ((uint2*)xb)[tid] = make_uint2(lo, hi);
}

// ---- pack W1/W2 (f32) into bf16 B-fragment layout: entry (kq, c) = W[kq*8+j][c], j=0..7 ----
__global__ __launch_bounds__(256) void k_pack_w(const float* __restrict__ W1, const float* __restrict__ W2,
                                                unsigned short* __restrict__ Wp1, unsigned short* __restrict__ Wp2) {
    int i = blockIdx.x * 256 + threadIdx.x;   // 3072 total
    if (i < 2048) {                           // W1: 16 kq x 128 c
        int kq = i >> 7, c = i & 127;
#pragma unroll
        for (int j = 0; j < 8; j++) Wp1[i * 8 + j] = f2bf(W1[(kq * 8 + j) * 128 + c]);
    } else if (i < 3072) {                    // W2: 16 kq x 64 c
        int i2 = i - 2048;
        int kq = i2 >> 6, c = i2 & 63;
#pragma unroll
        for (int j = 0; j < 8; j++) Wp2[i2 * 8 + j] = f2bf(W2[(kq * 8 + j) * 64 + c]);
    }
}

// ---- scan step 1: per-block (1024) sums of counts ----
__global__ __launch_bounds__(1024) void k_scan1(const int* __restrict__ cnt, int* __restrict__ bsum) {
    __shared__ int s[1024];
    int idx = blockIdx.x * 1024 + threadIdx.x;
    int v = (idx < N_NODES) ? cnt[idx] : 0;
    s[threadIdx.x] = v;
    __syncthreads();
    for (int o = 512; o > 0; o >>= 1) {
        if (threadIdx.x < o) s[threadIdx.x] += s[threadIdx.x + o];
        __syncthreads();
    }
    if (threadIdx.x == 0) bsum[blockIdx.x] = s[0];
}

// ---- scan step 2: exclusive-scan the 98 block sums (trivial) ----
__global__ void k_scan2(int* __restrict__ bsum, int nb, int* __restrict__ row_ptr) {
    if (threadIdx.x == 0 && blockIdx.x == 0) {
        int run = 0;
        for (int b = 0; b < nb; b++) { int v = bsum[b]; bsum[b] = run; run += v; }
        row_ptr[N_NODES] = run;   // == E
    }
}

// ---- scan step 3: per-block exclusive scan -> row_ptr, cursor ----
__global__ __launch_bounds__(1024) void k_scan3(const int* __restrict__ cnt, const int* __restrict__ bsum,
                                                int* __restrict__ row_ptr, int* __restrict__ cursor) {
    __shared__ int sa[1024], sb[1024];
    int idx = blockIdx.x * 1024 + threadIdx.x;
    int t = threadIdx.x;
    int v = (idx < N_NODES) ? cnt[idx] : 0;
    sa[t] = v;
    __syncthreads();
    int* cur = sa; int* nxt = sb;
    for (int o = 1; o < 1024; o <<= 1) {
        int val = cur[t] + (t >= o ? cur[t - o] : 0);
        nxt[t] = val;
        __syncthreads();
        int* tmp = cur; cur = nxt; nxt = tmp;
    }
    if (idx < N_NODES) {
        int rp = bsum[blockIdx.x] + cur[t] - v;   // exclusive
        row_ptr[idx] = rp;
        cursor[idx] = rp;
    }
}

// ---- scatter edges into CSR slots ----
__global__ __launch_bounds__(256) void k_fill(const int* __restrict__ src, const int* __restrict__ dst,
                                              int* __restrict__ cursor, int* __restrict__ csr_src) {
    int e = blockIdx.x * 256 + threadIdx.x;   // grid exactly E/256
    int d = dst[e];
    int p = atomicAdd(&cursor[d], 1);
    csr_src[p] = src[e];
}

// ---- layer-1 aggregation: wave per dst node, 128 bf16 cols (2/lane), f32 accum ----
__global__ __launch_bounds__(256) void k_agg1(const unsigned short* __restrict__ xb,
                                              const int* __restrict__ row_ptr, const int* __restrict__ csr,
                                              const float* __restrict__ in_norm,
                                              unsigned short* __restrict__ aggb) {
    int wave = threadIdx.x >> 6, lane = threadIdx.x & 63;
    int d = blockIdx.x * 4 + wave;
    if (d >= N_NODES) return;
    int e0 = row_ptr[d], e1 = row_ptr[d + 1];
    float a0 = 0.f, a1 = 0.f;
    for (int e = e0; e < e1; e++) {
        int s = __builtin_amdgcn_readfirstlane(csr[e]);
        unsigned int v = *(const unsigned int*)(xb + s * 128 + (lane << 1));
        a0 += bf2f((unsigned short)(v & 0xffffu));
        a1 += bf2f((unsigned short)(v >> 16));
    }
    float w = in_norm[d];
    unsigned int pk = (unsigned int)f2bf(a0 * w) | ((unsigned int)f2bf(a1 * w) << 16);
    *(unsigned int*)(aggb + d * 128 + (lane << 1)) = pk;
}

// ---- GEMM1: z = relu(agg1b @ W1 + b1); zs = bf16(z * out_norm) ----
__global__ __launch_bounds__(256) void k_gemm1(const unsigned short* __restrict__ Ab,
                                               const unsigned short* __restrict__ Wp,
                                               const float* __restrict__ bias,
                                               const float* __restrict__ out_norm,
                                               float* __restrict__ z_out,
                                               unsigned short* __restrict__ zs) {
    __shared__ __align__(16) unsigned short lds[16 * 128 * 8];   // 32 KB packed W1
    {
        const uint4* s4 = (const uint4*)Wp; uint4* d4 = (uint4*)lds;
        for (int i = threadIdx.x; i < 2048; i += 256) d4[i] = s4[i];
    }
    __syncthreads();
    int wave = threadIdx.x >> 6, lane = threadIdx.x & 63;
    int base = (blockIdx.x * 4 + wave) * 16;
    if (base >= N_NODES) return;   // N % 16 == 0, so waves are all-or-nothing
    int m = lane & 15, q = lane >> 4;
    short8 a[4];
#pragma unroll
    for (int t = 0; t < 4; t++) a[t] = *(const short8*)(Ab + (base + m) * 128 + t * 32 + q * 8);
    f32x4 acc[8];
#pragma unroll
    for (int c = 0; c < 8; c++) acc[c] = (f32x4)(0.f);
#pragma unroll
    for (int ct = 0; ct < 8; ct++) {
#pragma unroll
        for (int t = 0; t < 4; t++) {
            short8 b = *(const short8*)(lds + ((t * 4 + q) * 128 + ct * 16 + m) * 8);
            acc[ct] = __builtin_amdgcn_mfma_f32_16x16x32_bf16(a[t], b, acc[ct], 0, 0, 0);
        }
    }
    float onr[4];
#pragma unroll
    for (int i = 0; i < 4; i++) onr[i] = out_norm[base + q * 4 + i];
#pragma unroll
    for (int ct = 0; ct < 8; ct++) {
        int col = ct * 16 + m;
        float bv = bias[col];
#pragma unroll
        for (int i = 0; i < 4; i++) {
            int row = base + q * 4 + i;
            float v = acc[ct][i] + bv;
            v = v > 0.f ? v : 0.f;
            z_out[row * 128 + col] = v;
            zs[row * 128 + col] = f2bf(v * onr[i]);
        }
    }
}

// ---- GEMM2: t = zs @ W2 (N x 64, f32 out, no bias) ----
__global__ __launch_bounds__(256) void k_gemm2(const unsigned short* __restrict__ Ab,
                                               const unsigned short* __restrict__ Wp,
                                               float* __restrict__ t_out) {
    __shared__ __align__(16) unsigned short lds[16 * 64 * 8];   // 16 KB packed W2
    {
        const uint4* s4 = (const uint4*)Wp; uint4* d4 = (uint4*)lds;
        for (int i = threadIdx.x; i < 1024; i += 256) d4[i] = s4[i];
    }
    __syncthreads();
    int wave = threadIdx.x >> 6, lane = threadIdx.x & 63;
    int base = (blockIdx.x * 4 + wave) * 16;
    if (base >= N_NODES) return;
    int m = lane & 15, q = lane >> 4;
    short8 a[4];
#pragma unroll
    for (int t = 0; t < 4; t++) a[t] = *(const short8*)(Ab + (base + m) * 128 + t * 32 + q * 8);
    f32x4 acc[4];
#pragma unroll
    for (int c = 0; c < 4; c++) acc[c] = (f32x4)(0.f);
#pragma unroll
    for (int ct = 0; ct < 4; ct++) {
#pragma unroll
        for (int t = 0; t < 4; t++) {
            short8 b = *(const short8*)(lds + ((t * 4 + q) * 64 + ct * 16 + m) * 8);
            acc[ct] = __builtin_amdgcn_mfma_f32_16x16x32_bf16(a[t], b, acc[ct], 0, 0, 0);
        }
    }
#pragma unroll
    for (int ct = 0; ct < 4; ct++) {
        int col = ct * 16 + m;
#pragma unroll
        for (int i = 0; i < 4; i++) {
            int row = base + q * 4 + i;
            t_out[row * 64 + col] = acc[ct][i];
        }
    }
}

// ---- layer-2 aggregation: wave per dst node, 64 f32 cols (1/lane); epilogue *in_norm + b2 ----
__global__ __launch_bounds__(256) void k_agg2(const float* __restrict__ t,
                                              const int* __restrict__ row_ptr, const int* __restrict__ csr,
                                              const float* __restrict__ in_norm, const float* __restrict__ b2,
                                              float* __restrict__ out_h2) {
    int wave = threadIdx.x >> 6, lane = threadIdx.x & 63;
    int d = blockIdx.x * 4 + wave;
    if (d >= N_NODES) return;
    int e0 = row_ptr[d], e1 = row_ptr[d + 1];
    float acc = 0.f;
    for (int e = e0; e < e1; e++) {
        int s = __builtin_amdgcn_readfirstlane(csr[e]);
        acc += t[s * 64 + lane];
    }
    out_h2[d * 64 + lane] = acc * in_norm[d] + b2[lane];
}

extern "C" void kernel_launch(void* const* d_in, const int* in_sizes, int n_in,
                              void* d_out, int out_size, void* d_ws, size_t ws_size,
                              hipStream_t stream) {
    const float* x   = (const float*)d_in[0];
    const int*   src = (const int*)d_in[1];
    const int*   dst = (const int*)d_in[2];
    const float* W1  = (const float*)d_in[3];
    const float* b1  = (const float*)d_in[4];
    const float* W2  = (const float*)d_in[5];
    const float* b2  = (const float*)d_in[6];
    float* out_h2 = (float*)d_out;                     // [N,64]
    float* out_z  = (float*)d_out + N_NODES * 64;      // [N,128]

    char* ws = (char*)d_ws;
    size_t off = 0;
    auto alloc = [&](size_t bytes) -> char* {
        char* p = ws + off;
        off = (off + bytes + 255) & ~(size_t)255;
        return p;
    };
    int* deg_src  = (int*)alloc(N_NODES * 4);
    int* deg_dst  = (int*)alloc(N_NODES * 4);          // CSR counts
    int* row_ptr  = (int*)alloc((N_NODES + 1) * 4);
    int* cursor   = (int*)alloc(N_NODES * 4);
    int* bsum     = (int*)alloc(1024 * 4);
    float* out_norm = (float*)alloc(N_NODES * 4);
    float* in_norm  = (float*)alloc(N_NODES * 4);
    int* csr_src  = (int*)alloc((size_t)N_EDGES * 4);
    unsigned short* Wp1 = (unsigned short*)alloc(2048 * 8 * 2);
    unsigned short* Wp2 = (unsigned short*)alloc(1024 * 8 * 2);
    unsigned short* xb    = (unsigned short*)alloc((size_t)N_NODES * 128 * 2);
    unsigned short* agg1b = (unsigned short*)alloc((size_t)N_NODES * 128 * 2);
    unsigned short* zs    = (unsigned short*)alloc((size_t)N_NODES * 128 * 2);
    float* tbuf = (float*)alloc((size_t)N_NODES * 64 * 4);
    (void)ws_size; (void)in_sizes; (void)n_in; (void)out_size;

    hipMemsetAsync(deg_src, 0, N_NODES * 4, stream);
    hipMemsetAsync(deg_dst, 0, N_NODES * 4, stream);

    const int GD_E = N_EDGES / 256;          // 6250 exact
    const int GD_N = (N_NODES + 255) / 256;  // 391
    const int GD_SC = (N_NODES + 1023) / 1024; // 98
    const int GD_AGG = (N_NODES + 3) / 4;    // 25000
    const int GD_GEMM = (N_NODES / 16 + 3) / 4; // 1563

    k_deg<<<GD_E, 256, 0, stream>>>(src, dst, deg_src, deg_dst);
    k_norms<<<GD_N, 256, 0, stream>>>(deg_src, deg_dst, out_norm, in_norm);
    k_xb<<<N_NODES * 32 / 256, 256, 0, stream>>>(x, out_norm, xb);
    k_pack_w<<<12, 256, 0, stream>>>(W1, W2, Wp1, Wp2);
    k_scan1<<<GD_SC, 1024, 0, stream>>>(deg_dst, bsum);
    k_scan2<<<1, 1, 0, stream>>>(bsum, GD_SC, row_ptr);
    k_scan3<<<GD_SC, 1024, 0, stream>>>(deg_dst, bsum, row_ptr, cursor);
    k_fill<<<GD_E, 256, 0, stream>>>(src, dst, cursor, csr_src);
    k_agg1<<<GD_AGG, 256, 0, stream>>>(xb, row_ptr, csr_src, in_norm, agg1b);
    k_gemm1<<<GD_GEMM, 256, 0, stream>>>(agg1b, Wp1, b1, out_norm, out_z, zs);
    k_gemm2<<<GD_GEMM, 256, 0, stream>>>(zs, Wp2, tbuf);
    k_agg2<<<GD_AGG, 256, 0, stream>>>(tbuf, row_ptr, csr_src, in_norm, b2, out_h2);
}

// Round 2
// 540.552 us; speedup vs baseline: 1.3267x; 1.3267x over previous
//
#include <hip/hip_runtime.h>

#define N_NODES 100000
#define N_EDGES 1600000

typedef __attribute__((ext_vector_type(8))) short short8;   // 8 bf16 (4 VGPR) MFMA frag
typedef __attribute__((ext_vector_type(4))) float f32x4;    // MFMA accumulator

__device__ inline unsigned short f2bf(float f) {
    unsigned int u = __builtin_bit_cast(unsigned int, f);
    u += 0x7fffu + ((u >> 16) & 1u);   // round-to-nearest-even
    return (unsigned short)(u >> 16);
}
__device__ inline float bf2f(unsigned short h) {
    unsigned int u = ((unsigned int)h) << 16;
    return __builtin_bit_cast(float, u);
}

// ---- degree histogram (also CSR counts) ----
__global__ __launch_bounds__(256) void k_deg(const int* __restrict__ src, const int* __restrict__ dst,
                                             int* __restrict__ deg_src, int* __restrict__ deg_dst) {
    int e = blockIdx.x * 256 + threadIdx.x;   // grid sized exactly E/256
    atomicAdd(&deg_src[src[e]], 1);
    atomicAdd(&deg_dst[dst[e]], 1);
}

// ---- norms: deg>0 ? rsqrt(deg) : 1 ----
__global__ __launch_bounds__(256) void k_norms(const int* __restrict__ deg_src, const int* __restrict__ deg_dst,
                                               float* __restrict__ out_norm, float* __restrict__ in_norm) {
    int i = blockIdx.x * 256 + threadIdx.x;
    if (i >= N_NODES) return;
    int ds = deg_src[i], dd = deg_dst[i];
    out_norm[i] = ds > 0 ? rsqrtf((float)ds) : 1.0f;
    in_norm[i]  = dd > 0 ? rsqrtf((float)dd) : 1.0f;
}

// ---- xb = bf16(x * out_norm[row]) ----
__global__ __launch_bounds__(256) void k_xb(const float* __restrict__ x, const float* __restrict__ out_norm,
                                            unsigned short* __restrict__ xb) {
    int tid = blockIdx.x * 256 + threadIdx.x;   // grid exactly N*32
    int row = tid >> 5;
    float4 v = ((const float4*)x)[tid];
    float w = out_norm[row];
    unsigned int lo = (unsigned int)f2bf(v.x * w) | ((unsigned int)f2bf(v.y * w) << 16);
    unsigned int hi = (unsigned int)f2bf(v.z * w) | ((unsigned int)f2bf(v.w * w) << 16);
    ((uint2*)xb)[tid] = make_uint2(lo, hi);
}

// ---- pack W1/W2 (f32) into bf16 B-fragment layout: entry (kq, c) = W[kq*8+j][c], j=0..7 ----
__global__ __launch_bounds__(256) void k_pack_w(const float* __restrict__ W1, const float* __restrict__ W2,
                                                unsigned short* __restrict__ Wp1, unsigned short* __restrict__ Wp2) {
    int i = blockIdx.x * 256 + threadIdx.x;   // 3072 total
    if (i < 2048) {                           // W1: 16 kq x 128 c
        int kq = i >> 7, c = i & 127;
#pragma unroll
        for (int j = 0; j < 8; j++) Wp1[i * 8 + j] = f2bf(W1[(kq * 8 + j) * 128 + c]);
    } else if (i < 3072) {                    // W2: 16 kq x 64 c
        int i2 = i - 2048;
        int kq = i2 >> 6, c = i2 & 63;
#pragma unroll
        for (int j = 0; j < 8; j++) Wp2[i2 * 8 + j] = f2bf(W2[(kq * 8 + j) * 64 + c]);
    }
}

// ---- scan step 1: per-block (1024) sums of counts ----
__global__ __launch_bounds__(1024) void k_scan1(const int* __restrict__ cnt, int* __restrict__ bsum) {
    __shared__ int s[1024];
    int idx = blockIdx.x * 1024 + threadIdx.x;
    int v = (idx < N_NODES) ? cnt[idx] : 0;
    s[threadIdx.x] = v;
    __syncthreads();
    for (int o = 512; o > 0; o >>= 1) {
        if (threadIdx.x < o) s[threadIdx.x] += s[threadIdx.x + o];
        __syncthreads();
    }
    if (threadIdx.x == 0) bsum[blockIdx.x] = s[0];
}

// ---- scan step 2: exclusive-scan the 98 block sums (trivial) ----
__global__ void k_scan2(int* __restrict__ bsum, int nb, int* __restrict__ row_ptr) {
    if (threadIdx.x == 0 && blockIdx.x == 0) {
        int run = 0;
        for (int b = 0; b < nb; b++) { int v = bsum[b]; bsum[b] = run; run += v; }
        row_ptr[N_NODES] = run;   // == E
    }
}

// ---- scan step 3: per-block exclusive scan -> row_ptr, cursor ----
__global__ __launch_bounds__(1024) void k_scan3(const int* __restrict__ cnt, const int* __restrict__ bsum,
                                                int* __restrict__ row_ptr, int* __restrict__ cursor) {
    __shared__ int sa[1024], sb[1024];
    int idx = blockIdx.x * 1024 + threadIdx.x;
    int t = threadIdx.x;
    int v = (idx < N_NODES) ? cnt[idx] : 0;
    sa[t] = v;
    __syncthreads();
    int* cur = sa; int* nxt = sb;
    for (int o = 1; o < 1024; o <<= 1) {
        int val = cur[t] + (t >= o ? cur[t - o] : 0);
        nxt[t] = val;
        __syncthreads();
        int* tmp = cur; cur = nxt; nxt = tmp;
    }
    if (idx < N_NODES) {
        int rp = bsum[blockIdx.x] + cur[t] - v;   // exclusive
        row_ptr[idx] = rp;
        cursor[idx] = rp;
    }
}

// ---- scatter edges into CSR slots ----
__global__ __launch_bounds__(256) void k_fill(const int* __restrict__ src, const int* __restrict__ dst,
                                              int* __restrict__ cursor, int* __restrict__ csr_src) {
    int e = blockIdx.x * 256 + threadIdx.x;   // grid exactly E/256
    int d = dst[e];
    int p = atomicAdd(&cursor[d], 1);
    csr_src[p] = src[e];
}

// ---- layer-1 aggregation: wave per dst node, 128 bf16 cols (2/lane), f32 accum ----
// 8-deep unrolled gather: 8 independent row-loads in flight per wave to hide
// L2/L3 latency (latency-bound at 1-deep: 150us, VALUBusy 17%, HBM 17%).
__global__ __launch_bounds__(256) void k_agg1(const unsigned short* __restrict__ xb,
                                              const int* __restrict__ row_ptr, const int* __restrict__ csr,
                                              const float* __restrict__ in_norm,
                                              unsigned short* __restrict__ aggb) {
    int wave = threadIdx.x >> 6, lane = threadIdx.x & 63;
    int d = blockIdx.x * 4 + wave;
    if (d >= N_NODES) return;
    int e0 = __builtin_amdgcn_readfirstlane(row_ptr[d]);
    int e1 = __builtin_amdgcn_readfirstlane(row_ptr[d + 1]);
    int col = lane << 1;
    float accL[8], accH[8];
#pragma unroll
    for (int j = 0; j < 8; j++) { accL[j] = 0.f; accH[j] = 0.f; }
    int e = e0;
    for (; e + 8 <= e1; e += 8) {
        int sI[8];
#pragma unroll
        for (int j = 0; j < 8; j++) sI[j] = __builtin_amdgcn_readfirstlane(csr[e + j]);
        unsigned int v[8];
#pragma unroll
        for (int j = 0; j < 8; j++) v[j] = *(const unsigned int*)(xb + (size_t)sI[j] * 128 + col);
#pragma unroll
        for (int j = 0; j < 8; j++) {
            accL[j] += bf2f((unsigned short)(v[j] & 0xffffu));
            accH[j] += bf2f((unsigned short)(v[j] >> 16));
        }
    }
    for (; e < e1; e++) {
        int s = __builtin_amdgcn_readfirstlane(csr[e]);
        unsigned int v = *(const unsigned int*)(xb + (size_t)s * 128 + col);
        accL[0] += bf2f((unsigned short)(v & 0xffffu));
        accH[0] += bf2f((unsigned short)(v >> 16));
    }
    float a0 = 0.f, a1 = 0.f;
#pragma unroll
    for (int j = 0; j < 8; j++) { a0 += accL[j]; a1 += accH[j]; }
    float w = in_norm[d];
    unsigned int pk = (unsigned int)f2bf(a0 * w) | ((unsigned int)f2bf(a1 * w) << 16);
    *(unsigned int*)(aggb + (size_t)d * 128 + col) = pk;
}

// ---- GEMM1: z = relu(agg1b @ W1 + b1); zs = bf16(z * out_norm) ----
__global__ __launch_bounds__(256) void k_gemm1(const unsigned short* __restrict__ Ab,
                                               const unsigned short* __restrict__ Wp,
                                               const float* __restrict__ bias,
                                               const float* __restrict__ out_norm,
                                               float* __restrict__ z_out,
                                               unsigned short* __restrict__ zs) {
    __shared__ __align__(16) unsigned short lds[16 * 128 * 8];   // 32 KB packed W1
    {
        const uint4* s4 = (const uint4*)Wp; uint4* d4 = (uint4*)lds;
        for (int i = threadIdx.x; i < 2048; i += 256) d4[i] = s4[i];
    }
    __syncthreads();
    int wave = threadIdx.x >> 6, lane = threadIdx.x & 63;
    int base = (blockIdx.x * 4 + wave) * 16;
    if (base >= N_NODES) return;   // N % 16 == 0, so waves are all-or-nothing
    int m = lane & 15, q = lane >> 4;
    short8 a[4];
#pragma unroll
    for (int t = 0; t < 4; t++) a[t] = *(const short8*)(Ab + (size_t)(base + m) * 128 + t * 32 + q * 8);
    f32x4 acc[8];
#pragma unroll
    for (int c = 0; c < 8; c++) acc[c] = (f32x4)(0.f);
#pragma unroll
    for (int ct = 0; ct < 8; ct++) {
#pragma unroll
        for (int t = 0; t < 4; t++) {
            short8 b = *(const short8*)(lds + ((t * 4 + q) * 128 + ct * 16 + m) * 8);
            acc[ct] = __builtin_amdgcn_mfma_f32_16x16x32_bf16(a[t], b, acc[ct], 0, 0, 0);
        }
    }
    float onr[4];
#pragma unroll
    for (int i = 0; i < 4; i++) onr[i] = out_norm[base + q * 4 + i];
#pragma unroll
    for (int ct = 0; ct < 8; ct++) {
        int col = ct * 16 + m;
        float bv = bias[col];
#pragma unroll
        for (int i = 0; i < 4; i++) {
            int row = base + q * 4 + i;
            float v = acc[ct][i] + bv;
            v = v > 0.f ? v : 0.f;
            z_out[(size_t)row * 128 + col] = v;
            zs[(size_t)row * 128 + col] = f2bf(v * onr[i]);
        }
    }
}

// ---- GEMM2: t = zs @ W2 (N x 64, f32 out, no bias) ----
__global__ __launch_bounds__(256) void k_gemm2(const unsigned short* __restrict__ Ab,
                                               const unsigned short* __restrict__ Wp,
                                               float* __restrict__ t_out) {
    __shared__ __align__(16) unsigned short lds[16 * 64 * 8];   // 16 KB packed W2
    {
        const uint4* s4 = (const uint4*)Wp; uint4* d4 = (uint4*)lds;
        for (int i = threadIdx.x; i < 1024; i += 256) d4[i] = s4[i];
    }
    __syncthreads();
    int wave = threadIdx.x >> 6, lane = threadIdx.x & 63;
    int base = (blockIdx.x * 4 + wave) * 16;
    if (base >= N_NODES) return;
    int m = lane & 15, q = lane >> 4;
    short8 a[4];
#pragma unroll
    for (int t = 0; t < 4; t++) a[t] = *(const short8*)(Ab + (size_t)(base + m) * 128 + t * 32 + q * 8);
    f32x4 acc[4];
#pragma unroll
    for (int c = 0; c < 4; c++) acc[c] = (f32x4)(0.f);
#pragma unroll
    for (int ct = 0; ct < 4; ct++) {
#pragma unroll
        for (int t = 0; t < 4; t++) {
            short8 b = *(const short8*)(lds + ((t * 4 + q) * 64 + ct * 16 + m) * 8);
            acc[ct] = __builtin_amdgcn_mfma_f32_16x16x32_bf16(a[t], b, acc[ct], 0, 0, 0);
        }
    }
#pragma unroll
    for (int ct = 0; ct < 4; ct++) {
        int col = ct * 16 + m;
#pragma unroll
        for (int i = 0; i < 4; i++) {
            int row = base + q * 4 + i;
            t_out[(size_t)row * 64 + col] = acc[ct][i];
        }
    }
}

// ---- layer-2 aggregation: wave per dst node, 64 f32 cols (1/lane); epilogue *in_norm + b2 ----
// Same 8-deep unroll as k_agg1.
__global__ __launch_bounds__(256) void k_agg2(const float* __restrict__ t,
                                              const int* __restrict__ row_ptr, const int* __restrict__ csr,
                                              const float* __restrict__ in_norm, const float* __restrict__ b2,
                                              float* __restrict__ out_h2) {
    int wave = threadIdx.x >> 6, lane = threadIdx.x & 63;
    int d = blockIdx.x * 4 + wave;
    if (d >= N_NODES) return;
    int e0 = __builtin_amdgcn_readfirstlane(row_ptr[d]);
    int e1 = __builtin_amdgcn_readfirstlane(row_ptr[d + 1]);
    float acc[8];
#pragma unroll
    for (int j = 0; j < 8; j++) acc[j] = 0.f;
    int e = e0;
    for (; e + 8 <= e1; e += 8) {
        int sI[8];
#pragma unroll
        for (int j = 0; j < 8; j++) sI[j] = __builtin_amdgcn_readfirstlane(csr[e + j]);
        float v[8];
#pragma unroll
        for (int j = 0; j < 8; j++) v[j] = t[(size_t)sI[j] * 64 + lane];
#pragma unroll
        for (int j = 0; j < 8; j++) acc[j] += v[j];
    }
    for (; e < e1; e++) {
        int s = __builtin_amdgcn_readfirstlane(csr[e]);
        acc[0] += t[(size_t)s * 64 + lane];
    }
    float a = 0.f;
#pragma unroll
    for (int j = 0; j < 8; j++) a += acc[j];
    out_h2[(size_t)d * 64 + lane] = a * in_norm[d] + b2[lane];
}

extern "C" void kernel_launch(void* const* d_in, const int* in_sizes, int n_in,
                              void* d_out, int out_size, void* d_ws, size_t ws_size,
                              hipStream_t stream) {
    const float* x   = (const float*)d_in[0];
    const int*   src = (const int*)d_in[1];
    const int*   dst = (const int*)d_in[2];
    const float* W1  = (const float*)d_in[3];
    const float* b1  = (const float*)d_in[4];
    const float* W2  = (const float*)d_in[5];
    const float* b2  = (const float*)d_in[6];
    float* out_h2 = (float*)d_out;                     // [N,64]
    float* out_z  = (float*)d_out + N_NODES * 64;      // [N,128]

    char* ws = (char*)d_ws;
    size_t off = 0;
    auto alloc = [&](size_t bytes) -> char* {
        char* p = ws + off;
        off = (off + bytes + 255) & ~(size_t)255;
        return p;
    };
    int* deg_src  = (int*)alloc(N_NODES * 4);
    int* deg_dst  = (int*)alloc(N_NODES * 4);          // CSR counts
    int* row_ptr  = (int*)alloc((N_NODES + 1) * 4);
    int* cursor   = (int*)alloc(N_NODES * 4);
    int* bsum     = (int*)alloc(1024 * 4);
    float* out_norm = (float*)alloc(N_NODES * 4);
    float* in_norm  = (float*)alloc(N_NODES * 4);
    int* csr_src  = (int*)alloc((size_t)N_EDGES * 4);
    unsigned short* Wp1 = (unsigned short*)alloc(2048 * 8 * 2);
    unsigned short* Wp2 = (unsigned short*)alloc(1024 * 8 * 2);
    unsigned short* xb    = (unsigned short*)alloc((size_t)N_NODES * 128 * 2);
    unsigned short* agg1b = (unsigned short*)alloc((size_t)N_NODES * 128 * 2);
    unsigned short* zs    = (unsigned short*)alloc((size_t)N_NODES * 128 * 2);
    float* tbuf = (float*)alloc((size_t)N_NODES * 64 * 4);
    (void)ws_size; (void)in_sizes; (void)n_in; (void)out_size;

    hipMemsetAsync(deg_src, 0, N_NODES * 4, stream);
    hipMemsetAsync(deg_dst, 0, N_NODES * 4, stream);

    const int GD_E = N_EDGES / 256;          // 6250 exact
    const int GD_N = (N_NODES + 255) / 256;  // 391
    const int GD_SC = (N_NODES + 1023) / 1024; // 98
    const int GD_AGG = (N_NODES + 3) / 4;    // 25000
    const int GD_GEMM = (N_NODES / 16 + 3) / 4; // 1563

    k_deg<<<GD_E, 256, 0, stream>>>(src, dst, deg_src, deg_dst);
    k_norms<<<GD_N, 256, 0, stream>>>(deg_src, deg_dst, out_norm, in_norm);
    k_xb<<<N_NODES * 32 / 256, 256, 0, stream>>>(x, out_norm, xb);
    k_pack_w<<<12, 256, 0, stream>>>(W1, W2, Wp1, Wp2);
    k_scan1<<<GD_SC, 1024, 0, stream>>>(deg_dst, bsum);
    k_scan2<<<1, 1, 0, stream>>>(bsum, GD_SC, row_ptr);
    k_scan3<<<GD_SC, 1024, 0, stream>>>(deg_dst, bsum, row_ptr, cursor);
    k_fill<<<GD_E, 256, 0, stream>>>(src, dst, cursor, csr_src);
    k_agg1<<<GD_AGG, 256, 0, stream>>>(xb, row_ptr, csr_src, in_norm, agg1b);
    k_gemm1<<<GD_GEMM, 256, 0, stream>>>(agg1b, Wp1, b1, out_norm, out_z, zs);
    k_gemm2<<<GD_GEMM, 256, 0, stream>>>(zs, Wp2, tbuf);
    k_agg2<<<GD_AGG, 256, 0, stream>>>(tbuf, row_ptr, csr_src, in_norm, b2, out_h2);
}

// Round 3
// 397.959 us; speedup vs baseline: 1.8020x; 1.3583x over previous
//
#include <hip/hip_runtime.h>

#define N_NODES 100000
#define N_EDGES 1600000
#define NB 391          // coarse buckets of 256 dst nodes
#define BCAP 5120       // per-bucket capacity (expected 4096, 16-sigma headroom)
#define PART_BLOCKS 250
#define EPB 6400        // edges per partition block (250*6400 = 1.6M exact)

typedef __attribute__((ext_vector_type(8))) short short8;   // 8 bf16 (4 VGPR) MFMA frag
typedef __attribute__((ext_vector_type(4))) float f32x4;    // MFMA accumulator

__device__ inline unsigned short f2bf(float f) {
    unsigned int u = __builtin_bit_cast(unsigned int, f);
    u += 0x7fffu + ((u >> 16) & 1u);   // round-to-nearest-even
    return (unsigned short)(u >> 16);
}
__device__ inline float bf2f(unsigned short h) {
    unsigned int u = ((unsigned int)h) << 16;
    return __builtin_bit_cast(float, u);
}

// ---- out-degree histogram (src side only; in-degree comes from bucket sort) ----
__global__ __launch_bounds__(256) void k_deg(const int* __restrict__ src, int* __restrict__ deg_src) {
    int e = blockIdx.x * 256 + threadIdx.x;   // grid sized exactly E/256
    atomicAdd(&deg_src[src[e]], 1);
}

// ---- out_norm: deg>0 ? rsqrt(deg) : 1 ----
__global__ __launch_bounds__(256) void k_norms(const int* __restrict__ deg_src, float* __restrict__ out_norm) {
    int i = blockIdx.x * 256 + threadIdx.x;
    if (i >= N_NODES) return;
    int ds = deg_src[i];
    out_norm[i] = ds > 0 ? rsqrtf((float)ds) : 1.0f;
}

// ---- xb = bf16(x * out_norm[row]) ----
__global__ __launch_bounds__(256) void k_xb(const float* __restrict__ x, const float* __restrict__ out_norm,
                                            unsigned short* __restrict__ xb) {
    int tid = blockIdx.x * 256 + threadIdx.x;   // grid exactly N*32
    int row = tid >> 5;
    float4 v = ((const float4*)x)[tid];
    float w = out_norm[row];
    unsigned int lo = (unsigned int)f2bf(v.x * w) | ((unsigned int)f2bf(v.y * w) << 16);
    unsigned int hi = (unsigned int)f2bf(v.z * w) | ((unsigned int)f2bf(v.w * w) << 16);
    ((uint2*)xb)[tid] = make_uint2(lo, hi);
}

// ---- pack W1/W2 (f32) into bf16 B-fragment layout: entry (kq, c) = W[kq*8+j][c], j=0..7 ----
__global__ __launch_bounds__(256) void k_pack_w(const float* __restrict__ W1, const float* __restrict__ W2,
                                                unsigned short* __restrict__ Wp1, unsigned short* __restrict__ Wp2) {
    int i = blockIdx.x * 256 + threadIdx.x;   // 3072 total
    if (i < 2048) {                           // W1: 16 kq x 128 c
        int kq = i >> 7, c = i & 127;
#pragma unroll
        for (int j = 0; j < 8; j++) Wp1[i * 8 + j] = f2bf(W1[(kq * 8 + j) * 128 + c]);
    } else if (i < 3072) {                    // W2: 16 kq x 64 c
        int i2 = i - 2048;
        int kq = i2 >> 6, c = i2 & 63;
#pragma unroll
        for (int j = 0; j < 8; j++) Wp2[i2 * 8 + j] = f2bf(W2[(kq * 8 + j) * 64 + c]);
    }
}

// ---- partition: scatter edges into 391 coarse buckets (256 dst nodes each) ----
// LDS histogram + one global reservation atomic per (block,bucket): 98K atomics
// instead of 1.6M, and per-block runs keep csr-line writes within one XCD.
__global__ __launch_bounds__(256) void k_part(const int* __restrict__ src, const int* __restrict__ dst,
                                              int* __restrict__ gcur, unsigned int* __restrict__ ebuf) {
    __shared__ int hist[NB];
    __shared__ int gbase[NB];
    for (int i = threadIdx.x; i < NB; i += 256) hist[i] = 0;
    __syncthreads();
    int base = blockIdx.x * EPB;
    for (int i = threadIdx.x; i < EPB; i += 256) {
        int d = dst[base + i];
        atomicAdd(&hist[d >> 8], 1);
    }
    __syncthreads();
    for (int i = threadIdx.x; i < NB; i += 256) {
        gbase[i] = atomicAdd(&gcur[i], hist[i]);
        hist[i] = 0;                           // reuse as local run cursor
    }
    __syncthreads();
    for (int i = threadIdx.x; i < EPB; i += 256) {
        int d = dst[base + i], s = src[base + i];
        int b = d >> 8;
        int r = atomicAdd(&hist[b], 1);
        int pos = gbase[b] + r;
        if (pos < BCAP) ebuf[(size_t)b * BCAP + pos] = ((unsigned int)s << 8) | (unsigned int)(d & 255);
    }
}

// ---- exclusive scan of bucket counts -> bucket bases; row_ptr[N] = E ----
__global__ __launch_bounds__(512) void k_bscan(const int* __restrict__ gcur, int* __restrict__ bbase,
                                               int* __restrict__ row_ptr) {
    __shared__ int s[NB + 1];
    int t = threadIdx.x;
    if (t < NB) s[t] = min(gcur[t], BCAP);
    __syncthreads();
    if (t == 0) {
        int run = 0;
        for (int b = 0; b < NB; b++) { int v = s[b]; s[b] = run; run += v; }
        s[NB] = run;
    }
    __syncthreads();
    if (t < NB) bbase[t] = s[t];
    if (t == 0) { bbase[NB] = s[NB]; row_ptr[N_NODES] = s[NB]; }
}

// ---- per-bucket counting sort in LDS: emits coalesced csr_src, row_ptr, in_norm ----
__global__ __launch_bounds__(256) void k_bsort(const unsigned int* __restrict__ ebuf, const int* __restrict__ gcur,
                                               const int* __restrict__ bbase, int* __restrict__ csr_src,
                                               int* __restrict__ row_ptr, float* __restrict__ in_norm) {
    __shared__ unsigned int st[BCAP];   // 20 KB staged edges
    __shared__ int perm[BCAP];          // 20 KB sorted srcs
    __shared__ int hist[256], cursor[256], sa[256], sb[256];
    int b = blockIdx.x, t = threadIdx.x;
    int ne = min(gcur[b], BCAP);
    const unsigned int* eb = ebuf + (size_t)b * BCAP;
    hist[t] = 0;
    __syncthreads();
    for (int i = t; i < ne; i += 256) {
        unsigned int pk = eb[i];
        st[i] = pk;
        atomicAdd(&hist[pk & 255u], 1);
    }
    __syncthreads();
    // inclusive scan of hist (double-buffer Hillis-Steele over 256)
    sa[t] = hist[t];
    __syncthreads();
    int* cur = sa; int* nxt = sb;
    for (int o = 1; o < 256; o <<= 1) {
        int v = cur[t] + (t >= o ? cur[t - o] : 0);
        nxt[t] = v;
        __syncthreads();
        int* tmp = cur; cur = nxt; nxt = tmp;
    }
    int ex = cur[t] - hist[t];   // exclusive
    cursor[t] = ex;
    int node = b * 256 + t;
    if (node < N_NODES) {
        row_ptr[node] = bbase[b] + ex;
        in_norm[node] = hist[t] > 0 ? rsqrtf((float)hist[t]) : 1.0f;
    }
    __syncthreads();
    for (int i = t; i < ne; i += 256) {
        unsigned int pk = st[i];
        int pos = atomicAdd(&cursor[pk & 255u], 1);
        perm[pos] = (int)(pk >> 8);
    }
    __syncthreads();
    int gb = bbase[b];
    for (int i = t; i < ne; i += 256) csr_src[gb + i] = perm[i];
}

// ---- layer-1 aggregation: wave per dst node, 128 bf16 cols (2/lane), f32 accum ----
// 8-deep unrolled gather: 8 independent row-loads in flight per wave.
__global__ __launch_bounds__(256) void k_agg1(const unsigned short* __restrict__ xb,
                                              const int* __restrict__ row_ptr, const int* __restrict__ csr,
                                              const float* __restrict__ in_norm,
                                              unsigned short* __restrict__ aggb) {
    int wave = threadIdx.x >> 6, lane = threadIdx.x & 63;
    int d = blockIdx.x * 4 + wave;
    if (d >= N_NODES) return;
    int e0 = __builtin_amdgcn_readfirstlane(row_ptr[d]);
    int e1 = __builtin_amdgcn_readfirstlane(row_ptr[d + 1]);
    int col = lane << 1;
    float accL[8], accH[8];
#pragma unroll
    for (int j = 0; j < 8; j++) { accL[j] = 0.f; accH[j] = 0.f; }
    int e = e0;
    for (; e + 8 <= e1; e += 8) {
        int sI[8];
#pragma unroll
        for (int j = 0; j < 8; j++) sI[j] = __builtin_amdgcn_readfirstlane(csr[e + j]);
        unsigned int v[8];
#pragma unroll
        for (int j = 0; j < 8; j++) v[j] = *(const unsigned int*)(xb + (size_t)sI[j] * 128 + col);
#pragma unroll
        for (int j = 0; j < 8; j++) {
            accL[j] += bf2f((unsigned short)(v[j] & 0xffffu));
            accH[j] += bf2f((unsigned short)(v[j] >> 16));
        }
    }
    for (; e < e1; e++) {
        int s = __builtin_amdgcn_readfirstlane(csr[e]);
        unsigned int v = *(const unsigned int*)(xb + (size_t)s * 128 + col);
        accL[0] += bf2f((unsigned short)(v & 0xffffu));
        accH[0] += bf2f((unsigned short)(v >> 16));
    }
    float a0 = 0.f, a1 = 0.f;
#pragma unroll
    for (int j = 0; j < 8; j++) { a0 += accL[j]; a1 += accH[j]; }
    float w = in_norm[d];
    unsigned int pk = (unsigned int)f2bf(a0 * w) | ((unsigned int)f2bf(a1 * w) << 16);
    *(unsigned int*)(aggb + (size_t)d * 128 + col) = pk;
}

// ---- GEMM1: z = relu(agg1b @ W1 + b1); zs = bf16(z * out_norm) ----
__global__ __launch_bounds__(256) void k_gemm1(const unsigned short* __restrict__ Ab,
                                               const unsigned short* __restrict__ Wp,
                                               const float* __restrict__ bias,
                                               const float* __restrict__ out_norm,
                                               float* __restrict__ z_out,
                                               unsigned short* __restrict__ zs) {
    __shared__ __align__(16) unsigned short lds[16 * 128 * 8];   // 32 KB packed W1
    {
        const uint4* s4 = (const uint4*)Wp; uint4* d4 = (uint4*)lds;
        for (int i = threadIdx.x; i < 2048; i += 256) d4[i] = s4[i];
    }
    __syncthreads();
    int wave = threadIdx.x >> 6, lane = threadIdx.x & 63;
    int base = (blockIdx.x * 4 + wave) * 16;
    if (base >= N_NODES) return;   // N % 16 == 0, so waves are all-or-nothing
    int m = lane & 15, q = lane >> 4;
    short8 a[4];
#pragma unroll
    for (int t = 0; t < 4; t++) a[t] = *(const short8*)(Ab + (size_t)(base + m) * 128 + t * 32 + q * 8);
    f32x4 acc[8];
#pragma unroll
    for (int c = 0; c < 8; c++) acc[c] = (f32x4)(0.f);
#pragma unroll
    for (int ct = 0; ct < 8; ct++) {
#pragma unroll
        for (int t = 0; t < 4; t++) {
            short8 b = *(const short8*)(lds + ((t * 4 + q) * 128 + ct * 16 + m) * 8);
            acc[ct] = __builtin_amdgcn_mfma_f32_16x16x32_bf16(a[t], b, acc[ct], 0, 0, 0);
        }
    }
    float onr[4];
#pragma unroll
    for (int i = 0; i < 4; i++) onr[i] = out_norm[base + q * 4 + i];
#pragma unroll
    for (int ct = 0; ct < 8; ct++) {
        int col = ct * 16 + m;
        float bv = bias[col];
#pragma unroll
        for (int i = 0; i < 4; i++) {
            int row = base + q * 4 + i;
            float v = acc[ct][i] + bv;
            v = v > 0.f ? v : 0.f;
            z_out[(size_t)row * 128 + col] = v;
            zs[(size_t)row * 128 + col] = f2bf(v * onr[i]);
        }
    }
}

// ---- GEMM2: t = zs @ W2 (N x 64, f32 out, no bias) ----
__global__ __launch_bounds__(256) void k_gemm2(const unsigned short* __restrict__ Ab,
                                               const unsigned short* __restrict__ Wp,
                                               float* __restrict__ t_out) {
    __shared__ __align__(16) unsigned short lds[16 * 64 * 8];   // 16 KB packed W2
    {
        const uint4* s4 = (const uint4*)Wp; uint4* d4 = (uint4*)lds;
        for (int i = threadIdx.x; i < 1024; i += 256) d4[i] = s4[i];
    }
    __syncthreads();
    int wave = threadIdx.x >> 6, lane = threadIdx.x & 63;
    int base = (blockIdx.x * 4 + wave) * 16;
    if (base >= N_NODES) return;
    int m = lane & 15, q = lane >> 4;
    short8 a[4];
#pragma unroll
    for (int t = 0; t < 4; t++) a[t] = *(const short8*)(Ab + (size_t)(base + m) * 128 + t * 32 + q * 8);
    f32x4 acc[4];
#pragma unroll
    for (int c = 0; c < 4; c++) acc[c] = (f32x4)(0.f);
#pragma unroll
    for (int ct = 0; ct < 4; ct++) {
#pragma unroll
        for (int t = 0; t < 4; t++) {
            short8 b = *(const short8*)(lds + ((t * 4 + q) * 64 + ct * 16 + m) * 8);
            acc[ct] = __builtin_amdgcn_mfma_f32_16x16x32_bf16(a[t], b, acc[ct], 0, 0, 0);
        }
    }
#pragma unroll
    for (int ct = 0; ct < 4; ct++) {
        int col = ct * 16 + m;
#pragma unroll
        for (int i = 0; i < 4; i++) {
            int row = base + q * 4 + i;
            t_out[(size_t)row * 64 + col] = acc[ct][i];
        }
    }
}

// ---- layer-2 aggregation: wave per dst node, 64 f32 cols (1/lane) ----
__global__ __launch_bounds__(256) void k_agg2(const float* __restrict__ t,
                                              const int* __restrict__ row_ptr, const int* __restrict__ csr,
                                              const float* __restrict__ in_norm, const float* __restrict__ b2,
                                              float* __restrict__ out_h2) {
    int wave = threadIdx.x >> 6, lane = threadIdx.x & 63;
    int d = blockIdx.x * 4 + wave;
    if (d >= N_NODES) return;
    int e0 = __builtin_amdgcn_readfirstlane(row_ptr[d]);
    int e1 = __builtin_amdgcn_readfirstlane(row_ptr[d + 1]);
    float acc[8];
#pragma unroll
    for (int j = 0; j < 8; j++) acc[j] = 0.f;
    int e = e0;
    for (; e + 8 <= e1; e += 8) {
        int sI[8];
#pragma unroll
        for (int j = 0; j < 8; j++) sI[j] = __builtin_amdgcn_readfirstlane(csr[e + j]);
        float v[8];
#pragma unroll
        for (int j = 0; j < 8; j++) v[j] = t[(size_t)sI[j] * 64 + lane];
#pragma unroll
        for (int j = 0; j < 8; j++) acc[j] += v[j];
    }
    for (; e < e1; e++) {
        int s = __builtin_amdgcn_readfirstlane(csr[e]);
        acc[0] += t[(size_t)s * 64 + lane];
    }
    float a = 0.f;
#pragma unroll
    for (int j = 0; j < 8; j++) a += acc[j];
    out_h2[(size_t)d * 64 + lane] = a * in_norm[d] + b2[lane];
}

extern "C" void kernel_launch(void* const* d_in, const int* in_sizes, int n_in,
                              void* d_out, int out_size, void* d_ws, size_t ws_size,
                              hipStream_t stream) {
    const float* x   = (const float*)d_in[0];
    const int*   src = (const int*)d_in[1];
    const int*   dst = (const int*)d_in[2];
    const float* W1  = (const float*)d_in[3];
    const float* b1  = (const float*)d_in[4];
    const float* W2  = (const float*)d_in[5];
    const float* b2  = (const float*)d_in[6];
    float* out_h2 = (float*)d_out;                     // [N,64]
    float* out_z  = (float*)d_out + N_NODES * 64;      // [N,128]

    char* ws = (char*)d_ws;
    size_t off = 0;
    auto alloc = [&](size_t bytes) -> char* {
        char* p = ws + off;
        off = (off + bytes + 255) & ~(size_t)255;
        return p;
    };
    int* deg_src  = (int*)alloc(N_NODES * 4);
    int* gcur     = (int*)alloc(NB * 4);
    int* bbase    = (int*)alloc((NB + 1) * 4);
    int* row_ptr  = (int*)alloc((N_NODES + 1) * 4);
    float* out_norm = (float*)alloc(N_NODES * 4);
    float* in_norm  = (float*)alloc(N_NODES * 4);
    unsigned int* ebuf = (unsigned int*)alloc((size_t)NB * BCAP * 4);   // 8.0 MB
    int* csr_src  = (int*)alloc((size_t)N_EDGES * 4);
    unsigned short* Wp1 = (unsigned short*)alloc(2048 * 8 * 2);
    unsigned short* Wp2 = (unsigned short*)alloc(1024 * 8 * 2);
    unsigned short* xb    = (unsigned short*)alloc((size_t)N_NODES * 128 * 2);
    unsigned short* agg1b = (unsigned short*)alloc((size_t)N_NODES * 128 * 2);
    unsigned short* zs    = (unsigned short*)alloc((size_t)N_NODES * 128 * 2);
    float* tbuf = (float*)alloc((size_t)N_NODES * 64 * 4);
    (void)ws_size; (void)in_sizes; (void)n_in; (void)out_size;

    hipMemsetAsync(deg_src, 0, N_NODES * 4, stream);
    hipMemsetAsync(gcur, 0, NB * 4, stream);

    const int GD_E = N_EDGES / 256;          // 6250 exact
    const int GD_N = (N_NODES + 255) / 256;  // 391
    const int GD_AGG = (N_NODES + 3) / 4;    // 25000
    const int GD_GEMM = (N_NODES / 16 + 3) / 4; // 1563

    k_deg<<<GD_E, 256, 0, stream>>>(src, deg_src);
    k_norms<<<GD_N, 256, 0, stream>>>(deg_src, out_norm);
    k_xb<<<N_NODES * 32 / 256, 256, 0, stream>>>(x, out_norm, xb);
    k_pack_w<<<12, 256, 0, stream>>>(W1, W2, Wp1, Wp2);
    k_part<<<PART_BLOCKS, 256, 0, stream>>>(src, dst, gcur, ebuf);
    k_bscan<<<1, 512, 0, stream>>>(gcur, bbase, row_ptr);
    k_bsort<<<NB, 256, 0, stream>>>(ebuf, gcur, bbase, csr_src, row_ptr, in_norm);
    k_agg1<<<GD_AGG, 256, 0, stream>>>(xb, row_ptr, csr_src, in_norm, agg1b);
    k_gemm1<<<GD_GEMM, 256, 0, stream>>>(agg1b, Wp1, b1, out_norm, out_z, zs);
    k_gemm2<<<GD_GEMM, 256, 0, stream>>>(zs, Wp2, tbuf);
    k_agg2<<<GD_AGG, 256, 0, stream>>>(tbuf, row_ptr, csr_src, in_norm, b2, out_h2);
}

// Round 4
// 346.871 us; speedup vs baseline: 2.0674x; 1.1473x over previous
//
#include <hip/hip_runtime.h>

#define N_NODES 100000
#define N_EDGES 1600000
#define NB 391          // coarse buckets of 256 nodes
#define BCAP 5120       // per-bucket capacity (expected 4096, 16-sigma headroom)
#define PART_BLOCKS 250
#define EPB 6400        // edges per partition block (250*6400 = 1.6M exact)

typedef __attribute__((ext_vector_type(8))) short short8;   // 8 bf16 (4 VGPR) MFMA frag
typedef __attribute__((ext_vector_type(4))) float f32x4;    // MFMA accumulator

__device__ inline unsigned short f2bf(float f) {
    unsigned int u = __builtin_bit_cast(unsigned int, f);
    u += 0x7fffu + ((u >> 16) & 1u);   // round-to-nearest-even
    return (unsigned short)(u >> 16);
}
__device__ inline float bf2f(unsigned short h) {
    unsigned int u = ((unsigned int)h) << 16;
    return __builtin_bit_cast(float, u);
}

// ---- xb = bf16(x * out_norm[row]) ----
__global__ __launch_bounds__(256) void k_xb(const float* __restrict__ x, const float* __restrict__ out_norm,
                                            unsigned short* __restrict__ xb) {
    int tid = blockIdx.x * 256 + threadIdx.x;   // grid exactly N*32
    int row = tid >> 5;
    float4 v = ((const float4*)x)[tid];
    float w = out_norm[row];
    unsigned int lo = (unsigned int)f2bf(v.x * w) | ((unsigned int)f2bf(v.y * w) << 16);
    unsigned int hi = (unsigned int)f2bf(v.z * w) | ((unsigned int)f2bf(v.w * w) << 16);
    ((uint2*)xb)[tid] = make_uint2(lo, hi);
}

// ---- pack W1/W2 (f32) into bf16 B-fragment layout: entry (kq, c) = W[kq*8+j][c], j=0..7 ----
__global__ __launch_bounds__(256) void k_pack_w(const float* __restrict__ W1, const float* __restrict__ W2,
                                                unsigned short* __restrict__ Wp1, unsigned short* __restrict__ Wp2) {
    int i = blockIdx.x * 256 + threadIdx.x;   // 3072 total
    if (i < 2048) {                           // W1: 16 kq x 128 c
        int kq = i >> 7, c = i & 127;
#pragma unroll
        for (int j = 0; j < 8; j++) Wp1[i * 8 + j] = f2bf(W1[(kq * 8 + j) * 128 + c]);
    } else if (i < 3072) {                    // W2: 16 kq x 64 c
        int i2 = i - 2048;
        int kq = i2 >> 6, c = i2 & 63;
#pragma unroll
        for (int j = 0; j < 8; j++) Wp2[i2 * 8 + j] = f2bf(W2[(kq * 8 + j) * 64 + c]);
    }
}

// ---- partition: scatter edges into 391 dst-keyed buckets (full edge) AND 391
// src-keyed buckets (1 byte, for out-degree histogram). LDS histograms + one
// reservation atomic per (block,bucket): ~196K global atomics total, replacing
// k_deg's 1.6M random cross-XCD atomics (was 66us, 50MB WRITE for 400KB data).
__global__ __launch_bounds__(256) void k_part(const int* __restrict__ src, const int* __restrict__ dst,
                                              int* __restrict__ gcurD, int* __restrict__ gcurS,
                                              unsigned int* __restrict__ ebuf,
                                              unsigned char* __restrict__ ebufS) {
    __shared__ int histD[NB], gbaseD[NB];
    __shared__ int histS[NB], gbaseS[NB];
    for (int i = threadIdx.x; i < NB; i += 256) { histD[i] = 0; histS[i] = 0; }
    __syncthreads();
    int base = blockIdx.x * EPB;
    for (int i = threadIdx.x; i < EPB; i += 256) {
        int d = dst[base + i], s = src[base + i];
        atomicAdd(&histD[d >> 8], 1);
        atomicAdd(&histS[s >> 8], 1);
    }
    __syncthreads();
    for (int i = threadIdx.x; i < NB; i += 256) {
        gbaseD[i] = atomicAdd(&gcurD[i], histD[i]);
        gbaseS[i] = atomicAdd(&gcurS[i], histS[i]);
        histD[i] = 0;                          // reuse as local run cursors
        histS[i] = 0;
    }
    __syncthreads();
    for (int i = threadIdx.x; i < EPB; i += 256) {
        int d = dst[base + i], s = src[base + i];
        int bd = d >> 8;
        int r = atomicAdd(&histD[bd], 1);
        int pos = gbaseD[bd] + r;
        if (pos < BCAP) ebuf[(size_t)bd * BCAP + pos] = ((unsigned int)s << 8) | (unsigned int)(d & 255);
        int bs = s >> 8;
        int r2 = atomicAdd(&histS[bs], 1);
        int pos2 = gbaseS[bs] + r2;
        if (pos2 < BCAP) ebufS[(size_t)bs * BCAP + pos2] = (unsigned char)(s & 255);
    }
}

// ---- per-bucket out-degree histogram -> out_norm (replaces k_deg + k_norms) ----
__global__ __launch_bounds__(256) void k_bhist(const unsigned char* __restrict__ ebufS,
                                               const int* __restrict__ gcurS,
                                               float* __restrict__ out_norm) {
    __shared__ int hist[256];
    int b = blockIdx.x, t = threadIdx.x;
    hist[t] = 0;
    __syncthreads();
    int ne = min(gcurS[b], BCAP);
    const unsigned char* eb = ebufS + (size_t)b * BCAP;
    for (int i = t; i < ne; i += 256) atomicAdd(&hist[eb[i]], 1);
    __syncthreads();
    int node = b * 256 + t;
    if (node < N_NODES) out_norm[node] = hist[t] > 0 ? rsqrtf((float)hist[t]) : 1.0f;
}

// ---- exclusive scan of dst-bucket counts -> bucket bases; row_ptr[N] = E ----
__global__ __launch_bounds__(512) void k_bscan(const int* __restrict__ gcurD, int* __restrict__ bbase,
                                               int* __restrict__ row_ptr) {
    __shared__ int s[NB + 1];
    int t = threadIdx.x;
    if (t < NB) s[t] = min(gcurD[t], BCAP);
    __syncthreads();
    if (t == 0) {
        int run = 0;
        for (int b = 0; b < NB; b++) { int v = s[b]; s[b] = run; run += v; }
        s[NB] = run;
    }
    __syncthreads();
    if (t < NB) bbase[t] = s[t];
    if (t == 0) { bbase[NB] = s[NB]; row_ptr[N_NODES] = s[NB]; }
}

// ---- per-bucket counting sort in LDS: emits coalesced csr_src, row_ptr, in_norm ----
__global__ __launch_bounds__(256) void k_bsort(const unsigned int* __restrict__ ebuf, const int* __restrict__ gcurD,
                                               const int* __restrict__ bbase, int* __restrict__ csr_src,
                                               int* __restrict__ row_ptr, float* __restrict__ in_norm) {
    __shared__ unsigned int st[BCAP];   // 20 KB staged edges
    __shared__ int perm[BCAP];          // 20 KB sorted srcs
    __shared__ int hist[256], cursor[256], sa[256], sb[256];
    int b = blockIdx.x, t = threadIdx.x;
    int ne = min(gcurD[b], BCAP);
    const unsigned int* eb = ebuf + (size_t)b * BCAP;
    hist[t] = 0;
    __syncthreads();
    for (int i = t; i < ne; i += 256) {
        unsigned int pk = eb[i];
        st[i] = pk;
        atomicAdd(&hist[pk & 255u], 1);
    }
    __syncthreads();
    // inclusive scan of hist (double-buffer Hillis-Steele over 256)
    sa[t] = hist[t];
    __syncthreads();
    int* cur = sa; int* nxt = sb;
    for (int o = 1; o < 256; o <<= 1) {
        int v = cur[t] + (t >= o ? cur[t - o] : 0);
        nxt[t] = v;
        __syncthreads();
        int* tmp = cur; cur = nxt; nxt = tmp;
    }
    int ex = cur[t] - hist[t];   // exclusive
    cursor[t] = ex;
    int node = b * 256 + t;
    if (node < N_NODES) {
        row_ptr[node] = bbase[b] + ex;
        in_norm[node] = hist[t] > 0 ? rsqrtf((float)hist[t]) : 1.0f;
    }
    __syncthreads();
    for (int i = t; i < ne; i += 256) {
        unsigned int pk = st[i];
        int pos = atomicAdd(&cursor[pk & 255u], 1);
        perm[pos] = (int)(pk >> 8);
    }
    __syncthreads();
    int gb = bbase[b];
    for (int i = t; i < ne; i += 256) csr_src[gb + i] = perm[i];
}

// ---- layer-1 aggregation: wave per dst node, 128 bf16 cols (2/lane), f32 accum ----
// 8-deep unrolled gather: 8 independent row-loads in flight per wave.
__global__ __launch_bounds__(256) void k_agg1(const unsigned short* __restrict__ xb,
                                              const int* __restrict__ row_ptr, const int* __restrict__ csr,
                                              const float* __restrict__ in_norm,
                                              unsigned short* __restrict__ aggb) {
    int wave = threadIdx.x >> 6, lane = threadIdx.x & 63;
    int d = blockIdx.x * 4 + wave;
    if (d >= N_NODES) return;
    int e0 = __builtin_amdgcn_readfirstlane(row_ptr[d]);
    int e1 = __builtin_amdgcn_readfirstlane(row_ptr[d + 1]);
    int col = lane << 1;
    float accL[8], accH[8];
#pragma unroll
    for (int j = 0; j < 8; j++) { accL[j] = 0.f; accH[j] = 0.f; }
    int e = e0;
    for (; e + 8 <= e1; e += 8) {
        int sI[8];
#pragma unroll
        for (int j = 0; j < 8; j++) sI[j] = __builtin_amdgcn_readfirstlane(csr[e + j]);
        unsigned int v[8];
#pragma unroll
        for (int j = 0; j < 8; j++) v[j] = *(const unsigned int*)(xb + (size_t)sI[j] * 128 + col);
#pragma unroll
        for (int j = 0; j < 8; j++) {
            accL[j] += bf2f((unsigned short)(v[j] & 0xffffu));
            accH[j] += bf2f((unsigned short)(v[j] >> 16));
        }
    }
    for (; e < e1; e++) {
        int s = __builtin_amdgcn_readfirstlane(csr[e]);
        unsigned int v = *(const unsigned int*)(xb + (size_t)s * 128 + col);
        accL[0] += bf2f((unsigned short)(v & 0xffffu));
        accH[0] += bf2f((unsigned short)(v >> 16));
    }
    float a0 = 0.f, a1 = 0.f;
#pragma unroll
    for (int j = 0; j < 8; j++) { a0 += accL[j]; a1 += accH[j]; }
    float w = in_norm[d];
    unsigned int pk = (unsigned int)f2bf(a0 * w) | ((unsigned int)f2bf(a1 * w) << 16);
    *(unsigned int*)(aggb + (size_t)d * 128 + col) = pk;
}

// ---- GEMM1: z = relu(agg1b @ W1 + b1); zs = bf16(z * out_norm) ----
__global__ __launch_bounds__(256) void k_gemm1(const unsigned short* __restrict__ Ab,
                                               const unsigned short* __restrict__ Wp,
                                               const float* __restrict__ bias,
                                               const float* __restrict__ out_norm,
                                               float* __restrict__ z_out,
                                               unsigned short* __restrict__ zs) {
    __shared__ __align__(16) unsigned short lds[16 * 128 * 8];   // 32 KB packed W1
    {
        const uint4* s4 = (const uint4*)Wp; uint4* d4 = (uint4*)lds;
        for (int i = threadIdx.x; i < 2048; i += 256) d4[i] = s4[i];
    }
    __syncthreads();
    int wave = threadIdx.x >> 6, lane = threadIdx.x & 63;
    int base = (blockIdx.x * 4 + wave) * 16;
    if (base >= N_NODES) return;   // N % 16 == 0, so waves are all-or-nothing
    int m = lane & 15, q = lane >> 4;
    short8 a[4];
#pragma unroll
    for (int t = 0; t < 4; t++) a[t] = *(const short8*)(Ab + (size_t)(base + m) * 128 + t * 32 + q * 8);
    f32x4 acc[8];
#pragma unroll
    for (int c = 0; c < 8; c++) acc[c] = (f32x4)(0.f);
#pragma unroll
    for (int ct = 0; ct < 8; ct++) {
#pragma unroll
        for (int t = 0; t < 4; t++) {
            short8 b = *(const short8*)(lds + ((t * 4 + q) * 128 + ct * 16 + m) * 8);
            acc[ct] = __builtin_amdgcn_mfma_f32_16x16x32_bf16(a[t], b, acc[ct], 0, 0, 0);
        }
    }
    float onr[4];
#pragma unroll
    for (int i = 0; i < 4; i++) onr[i] = out_norm[base + q * 4 + i];
#pragma unroll
    for (int ct = 0; ct < 8; ct++) {
        int col = ct * 16 + m;
        float bv = bias[col];
#pragma unroll
        for (int i = 0; i < 4; i++) {
            int row = base + q * 4 + i;
            float v = acc[ct][i] + bv;
            v = v > 0.f ? v : 0.f;
            z_out[(size_t)row * 128 + col] = v;
            zs[(size_t)row * 128 + col] = f2bf(v * onr[i]);
        }
    }
}

// ---- GEMM2: t = zs @ W2 (N x 64, f32 out, no bias) ----
__global__ __launch_bounds__(256) void k_gemm2(const unsigned short* __restrict__ Ab,
                                               const unsigned short* __restrict__ Wp,
                                               float* __restrict__ t_out) {
    __shared__ __align__(16) unsigned short lds[16 * 64 * 8];   // 16 KB packed W2
    {
        const uint4* s4 = (const uint4*)Wp; uint4* d4 = (uint4*)lds;
        for (int i = threadIdx.x; i < 1024; i += 256) d4[i] = s4[i];
    }
    __syncthreads();
    int wave = threadIdx.x >> 6, lane = threadIdx.x & 63;
    int base = (blockIdx.x * 4 + wave) * 16;
    if (base >= N_NODES) return;
    int m = lane & 15, q = lane >> 4;
    short8 a[4];
#pragma unroll
    for (int t = 0; t < 4; t++) a[t] = *(const short8*)(Ab + (size_t)(base + m) * 128 + t * 32 + q * 8);
    f32x4 acc[4];
#pragma unroll
    for (int c = 0; c < 4; c++) acc[c] = (f32x4)(0.f);
#pragma unroll
    for (int ct = 0; ct < 4; ct++) {
#pragma unroll
        for (int t = 0; t < 4; t++) {
            short8 b = *(const short8*)(lds + ((t * 4 + q) * 64 + ct * 16 + m) * 8);
            acc[ct] = __builtin_amdgcn_mfma_f32_16x16x32_bf16(a[t], b, acc[ct], 0, 0, 0);
        }
    }
#pragma unroll
    for (int ct = 0; ct < 4; ct++) {
        int col = ct * 16 + m;
#pragma unroll
        for (int i = 0; i < 4; i++) {
            int row = base + q * 4 + i;
            t_out[(size_t)row * 64 + col] = acc[ct][i];
        }
    }
}

// ---- layer-2 aggregation: wave per dst node, 64 f32 cols (1/lane) ----
__global__ __launch_bounds__(256) void k_agg2(const float* __restrict__ t,
                                              const int* __restrict__ row_ptr, const int* __restrict__ csr,
                                              const float* __restrict__ in_norm, const float* __restrict__ b2,
                                              float* __restrict__ out_h2) {
    int wave = threadIdx.x >> 6, lane = threadIdx.x & 63;
    int d = blockIdx.x * 4 + wave;
    if (d >= N_NODES) return;
    int e0 = __builtin_amdgcn_readfirstlane(row_ptr[d]);
    int e1 = __builtin_amdgcn_readfirstlane(row_ptr[d + 1]);
    float acc[8];
#pragma unroll
    for (int j = 0; j < 8; j++) acc[j] = 0.f;
    int e = e0;
    for (; e + 8 <= e1; e += 8) {
        int sI[8];
#pragma unroll
        for (int j = 0; j < 8; j++) sI[j] = __builtin_amdgcn_readfirstlane(csr[e + j]);
        float v[8];
#pragma unroll
        for (int j = 0; j < 8; j++) v[j] = t[(size_t)sI[j] * 64 + lane];
#pragma unroll
        for (int j = 0; j < 8; j++) acc[j] += v[j];
    }
    for (; e < e1; e++) {
        int s = __builtin_amdgcn_readfirstlane(csr[e]);
        acc[0] += t[(size_t)s * 64 + lane];
    }
    float a = 0.f;
#pragma unroll
    for (int j = 0; j < 8; j++) a += acc[j];
    out_h2[(size_t)d * 64 + lane] = a * in_norm[d] + b2[lane];
}

extern "C" void kernel_launch(void* const* d_in, const int* in_sizes, int n_in,
                              void* d_out, int out_size, void* d_ws, size_t ws_size,
                              hipStream_t stream) {
    const float* x   = (const float*)d_in[0];
    const int*   src = (const int*)d_in[1];
    const int*   dst = (const int*)d_in[2];
    const float* W1  = (const float*)d_in[3];
    const float* b1  = (const float*)d_in[4];
    const float* W2  = (const float*)d_in[5];
    const float* b2  = (const float*)d_in[6];
    float* out_h2 = (float*)d_out;                     // [N,64]
    float* out_z  = (float*)d_out + N_NODES * 64;      // [N,128]

    char* ws = (char*)d_ws;
    size_t off = 0;
    auto alloc = [&](size_t bytes) -> char* {
        char* p = ws + off;
        off = (off + bytes + 255) & ~(size_t)255;
        return p;
    };
    int* gcurD    = (int*)alloc(NB * 4);
    int* gcurS    = (int*)alloc(NB * 4);
    int* bbase    = (int*)alloc((NB + 1) * 4);
    int* row_ptr  = (int*)alloc((N_NODES + 1) * 4);
    float* out_norm = (float*)alloc(N_NODES * 4);
    float* in_norm  = (float*)alloc(N_NODES * 4);
    unsigned int* ebuf = (unsigned int*)alloc((size_t)NB * BCAP * 4);        // 8.0 MB
    unsigned char* ebufS = (unsigned char*)alloc((size_t)NB * BCAP);         // 2.0 MB
    int* csr_src  = (int*)alloc((size_t)N_EDGES * 4);
    unsigned short* Wp1 = (unsigned short*)alloc(2048 * 8 * 2);
    unsigned short* Wp2 = (unsigned short*)alloc(1024 * 8 * 2);
    unsigned short* xb    = (unsigned short*)alloc((size_t)N_NODES * 128 * 2);
    unsigned short* agg1b = (unsigned short*)alloc((size_t)N_NODES * 128 * 2);
    unsigned short* zs    = (unsigned short*)alloc((size_t)N_NODES * 128 * 2);
    float* tbuf = (float*)alloc((size_t)N_NODES * 64 * 4);
    (void)ws_size; (void)in_sizes; (void)n_in; (void)out_size;

    hipMemsetAsync(gcurD, 0, NB * 4, stream);
    hipMemsetAsync(gcurS, 0, NB * 4, stream);

    const int GD_AGG = (N_NODES + 3) / 4;       // 25000
    const int GD_GEMM = (N_NODES / 16 + 3) / 4; // 1563

    k_part<<<PART_BLOCKS, 256, 0, stream>>>(src, dst, gcurD, gcurS, ebuf, ebufS);
    k_bhist<<<NB, 256, 0, stream>>>(ebufS, gcurS, out_norm);
    k_bscan<<<1, 512, 0, stream>>>(gcurD, bbase, row_ptr);
    k_bsort<<<NB, 256, 0, stream>>>(ebuf, gcurD, bbase, csr_src, row_ptr, in_norm);
    k_xb<<<N_NODES * 32 / 256, 256, 0, stream>>>(x, out_norm, xb);
    k_pack_w<<<12, 256, 0, stream>>>(W1, W2, Wp1, Wp2);
    k_agg1<<<GD_AGG, 256, 0, stream>>>(xb, row_ptr, csr_src, in_norm, agg1b);
    k_gemm1<<<GD_GEMM, 256, 0, stream>>>(agg1b, Wp1, b1, out_norm, out_z, zs);
    k_gemm2<<<GD_GEMM, 256, 0, stream>>>(zs, Wp2, tbuf);
    k_agg2<<<GD_AGG, 256, 0, stream>>>(tbuf, row_ptr, csr_src, in_norm, b2, out_h2);
}